// Round 6
// baseline (15716.054 us; speedup 1.0000x reference)
//
#include <hip/hip_runtime.h>

typedef __bf16 bf16x8 __attribute__((ext_vector_type(8)));
typedef float  f32x4  __attribute__((ext_vector_type(4)));
typedef unsigned short u16;
typedef unsigned int   u32;
typedef unsigned long long u64;

#define NB 128      // batch
#define NT 1024     // time steps
#define NF 128      // input features
#define NH 256      // hidden units
#define NG 1024     // 4*NH gate columns
#define M_ROWS (NB*NT)

// flags layout (u32 offsets). sc0-touched lines are 256B-per-chain padded so
// no two XCDs ever dirty the same L2 line.
#define CNT1_OFF  0      // + g*16  agent-mode L1 counters (round-4 protocol)
#define CNT2_OFF  128    // + g*16  agent-mode L2 counters
#define TAGS1_OFF 256    // + g*64 + j   fast-mode L1 per-WG tags (256B/group)
#define TAGS2_OFF 768    // + g*64 + j   fast-mode L2 tags
#define PING_OFF  1280   // + g*64 + r   sc0 liveness ring (r=0..7)
#define REGX_OFF  1792   // + x*16  per-XCD arrival counters
#define REGC_OFF  1920   //         global registration counter
#define ABRT_OFF  1936   // + g     chain abort flag (agent)
#define DONE_OFF  1952   // + g     chain join counter (agent)
#define FLAGS_N   2048

__device__ __forceinline__ u16 f2bf(float f) {
  union { float f; u32 u; } c; c.f = f;
  u32 u = c.u;
  return (u16)((u + 0x7fffu + ((u >> 16) & 1u)) >> 16);   // RNE
}
__device__ __forceinline__ float sigm(float x) { return 1.f / (1.f + __expf(-x)); }
__device__ __forceinline__ float tanh_(float x) { return 1.f - 2.f / (1.f + __expf(2.f * x)); }
__device__ __forceinline__ f32x4 mm(bf16x8 a, bf16x8 b, f32x4 c) {
  return __builtin_amdgcn_mfma_f32_16x16x32_bf16(a, b, c, 0, 0, 0);
}
__device__ __forceinline__ void vm0() { asm volatile("s_waitcnt vmcnt(0)" ::: "memory"); }
__device__ __forceinline__ void sb0() { __builtin_amdgcn_sched_barrier(0); }

// ---- agent primitives (MALL coherence point; HW-proven rounds 4/5) ----
__device__ __forceinline__ u32 a_ld32(const u32* p) { return __hip_atomic_load((u32*)p, __ATOMIC_RELAXED, __HIP_MEMORY_SCOPE_AGENT); }
__device__ __forceinline__ u64 a_ld64(const u64* p) { return __hip_atomic_load((u64*)p, __ATOMIC_RELAXED, __HIP_MEMORY_SCOPE_AGENT); }
__device__ __forceinline__ void a_st32(u32* p, u32 v) { __hip_atomic_store(p, v, __ATOMIC_RELAXED, __HIP_MEMORY_SCOPE_AGENT); }
__device__ __forceinline__ void a_st64(u64* p, u64 v) { __hip_atomic_store(p, v, __ATOMIC_RELAXED, __HIP_MEMORY_SCOPE_AGENT); }
__device__ __forceinline__ void a_add32(u32* p, u32 v) { __hip_atomic_fetch_add(p, v, __ATOMIC_RELAXED, __HIP_MEMORY_SCOPE_AGENT); }
__device__ __forceinline__ u32 a_addret(u32* p, u32 v) { return __hip_atomic_fetch_add(p, v, __ATOMIC_RELAXED, __HIP_MEMORY_SCOPE_AGENT); }

// ---- sc0 primitives: bypass L1, serviced at the XCD-shared L2. Enabled per
// chain only after (a) actual-placement co-location and (b) a live ping-ring
// test over the exact poll pattern. ----
__device__ __forceinline__ u64 s_ld64(const u64* p) {
  u64 r; asm volatile("global_load_dwordx2 %0, %1, off sc0" : "=v"(r) : "v"(p) : "memory"); return r;
}
__device__ __forceinline__ u32 s_ld32w(const u32* p) {
  u32 r; asm volatile("global_load_dword %0, %1, off sc0\n\ts_waitcnt vmcnt(0)" : "=v"(r) : "v"(p) : "memory"); return r;
}
__device__ __forceinline__ void s_st64(u64* p, u64 v) {
  asm volatile("global_store_dwordx2 %0, %1, off sc0" :: "v"(p), "v"(v) : "memory");
}
__device__ __forceinline__ void s_st32(u32* p, u32 v) {
  asm volatile("global_store_dword %0, %1, off sc0" :: "v"(p), "v"(v) : "memory");
}

// agent poll: single counter >= target (round-4 proven)
__device__ __forceinline__ bool poll_ge(u32* c, u32 target, long& budget) {
  while (a_ld32(c) < target) { if (--budget <= 0) return false; }
  asm volatile("" ::: "memory");
  return true;
}
// fast poll: 4 per-WG tags (16B) all >= target
__device__ __forceinline__ bool poll4(const u32* tg, u32 target, long& budget) {
  const u64* p = (const u64*)tg;
  for (;;) {
    u64 a = s_ld64(p), b = s_ld64(p + 1);
    vm0(); sb0();
    if ((u32)a >= target && (u32)(a >> 32) >= target &&
        (u32)b >= target && (u32)(b >> 32) >= target) break;
    if (--budget <= 0) return false;
  }
  asm volatile("" ::: "memory");
  return true;
}

// ---------------------------------------------------------------------------
__global__ void prep(u32* __restrict__ flags) {
  int i = blockIdx.x * 256 + threadIdx.x;
  if (i < FLAGS_N) flags[i] = 0;
}

// ---------------------------------------------------------------------------
// One layer's scan. Arithmetic identical to rounds 2-5 (absmax 9.77e-4).
// FAST: sc0 tag protocol (XCD-local L2). !FAST: round-4 agent fetch_add.
// ---------------------------------------------------------------------------
template<bool IS1, bool FAST>
__device__ void scan(const float* __restrict__ U, const float* __restrict__ W,
                     const float* __restrict__ bias, const float* __restrict__ xf,
                     u64* hseq, u64* h2, u32* flags, float* hlast,
                     int g, int j, float (*gl)[16][68])
{
  const int tid = threadIdx.x, lane = tid & 63, w = tid >> 6;
  const int l15 = lane & 15, l16 = lane >> 4;
  constexpr int KIN  = IS1 ? NF : NH;
  constexpr int KTIN = KIN / 32;
  const int colb = w * NH + j * 64;

  // Resident W frags (B-operand), K = KIN
  bf16x8 wfr[KTIN][4];
#pragma unroll
  for (int kt = 0; kt < KTIN; ++kt) {
    const int k0 = kt * 32 + l16 * 8;
#pragma unroll
    for (int nt = 0; nt < 4; ++nt) {
      const float* wp = W + (long)k0 * NG + colb + nt * 16 + l15;
      union { u16 s[8]; bf16x8 v; } cv;
#pragma unroll
      for (int e = 0; e < 8; ++e) cv.s[e] = f2bf(wp[(long)e * NG]);
      wfr[kt][nt] = cv.v;
    }
  }
  // Resident U frags (B-operand), K = NH
  bf16x8 ufr[8][4];
#pragma unroll
  for (int kt = 0; kt < 8; ++kt) {
    const int k0 = kt * 32 + l16 * 8;
#pragma unroll
    for (int nt = 0; nt < 4; ++nt) {
      const float* up = U + (long)k0 * NG + colb + nt * 16 + l15;
      union { u16 s[8]; bf16x8 v; } cv;
#pragma unroll
      for (int e = 0; e < 8; ++e) cv.s[e] = f2bf(up[(long)e * NG]);
      ufr[kt][nt] = cv.v;
    }
  }

  const int prow = tid & 15, ublk = tid >> 4;
  const int b = g * 16 + prow, ucol = j * 64 + ublk * 4;

  float bv[4][4];
#pragma unroll
  for (int gg = 0; gg < 4; ++gg)
#pragma unroll
    for (int q = 0; q < 4; ++q) bv[gg][q] = bias[gg * NH + ucol + q];

  u32* c1 = flags + CNT1_OFF + g * 16;
  u32* c2 = flags + CNT2_OFF + g * 16;
  u32* t1 = flags + TAGS1_OFF + g * 64;
  u32* t2 = flags + TAGS2_OFF + g * 64;
  u32* mytag = (IS1 ? t1 : t2) + j;
  const long abatch = (long)(g * 16 + l15) * NT;

  float cst[4] = {0.f, 0.f, 0.f, 0.f};
  long budget = FAST ? 5000000 : 20000000;
  bool dead = false;

  for (int t = 0; t < NT; ++t) {
    // ---- input A-frags ----
    bf16x8 ax[KTIN];
    if constexpr (IS1) {
      const float* xp0 = xf + (abatch + t) * NF;
      f32x4 xraw[KTIN][2];
#pragma unroll
      for (int kt = 0; kt < KTIN; ++kt) {
        const float* xp = xp0 + kt * 32 + l16 * 8;
        xraw[kt][0] = *reinterpret_cast<const f32x4*>(xp);
        xraw[kt][1] = *reinterpret_cast<const f32x4*>(xp + 4);
      }
#pragma unroll
      for (int kt = 0; kt < KTIN; ++kt) {
        union { u16 s[8]; bf16x8 v; } cv;
#pragma unroll
        for (int e = 0; e < 4; ++e) {
          cv.s[e] = f2bf(xraw[kt][0][e]); cv.s[4 + e] = f2bf(xraw[kt][1][e]);
        }
        ax[kt] = cv.v;
      }
    } else {
      // feed gate: hseq column t fully published by L1
      if (!dead) {
        bool okp;
        if constexpr (FAST) okp = poll4(t1, (u32)(t + 1), budget);
        else                okp = poll_ge(c1, 16u * (u32)(t + 1), budget);
        if (!okp) dead = true;
      }
      u64* xb = hseq + (abatch + t) * 64;
      u64 xr[KTIN][2];
#pragma unroll
      for (int kt = 0; kt < KTIN; ++kt) {
        if constexpr (FAST) {
          xr[kt][0] = s_ld64(xb + kt * 8 + l16 * 2);
          xr[kt][1] = s_ld64(xb + kt * 8 + l16 * 2 + 1);
        } else {
          xr[kt][0] = a_ld64(xb + kt * 8 + l16 * 2);
          xr[kt][1] = a_ld64(xb + kt * 8 + l16 * 2 + 1);
        }
      }
      if constexpr (FAST) { vm0(); sb0(); }
#pragma unroll
      for (int kt = 0; kt < KTIN; ++kt) {
        union { u64 q[2]; bf16x8 v; } cv;
        cv.q[0] = xr[kt][0]; cv.q[1] = xr[kt][1];
        ax[kt] = cv.v;
      }
    }

    f32x4 acc[4] = {};
#pragma unroll
    for (int kt = 0; kt < KTIN; ++kt)
#pragma unroll
      for (int nt = 0; nt < 4; ++nt) acc[nt] = mm(ax[kt], wfr[kt][nt], acc[nt]);

    // ---- recurrent A-frags ----
    if (t > 0) {
      if (!dead) {
        bool okp;
        if constexpr (FAST) okp = poll4(IS1 ? t1 : t2, (u32)t, budget);
        else                okp = poll_ge(IS1 ? c1 : c2, 16u * (u32)t, budget);
        if (!okp) dead = true;
      }
      const u64* hb;
      if constexpr (IS1) hb = hseq + (abatch + (t - 1)) * 64;
      else               hb = h2 + ((((long)((t + 1) & 1) * 8 + g) * 16) + l15) * 64;
      u64 hr[8][2];
#pragma unroll
      for (int kt = 0; kt < 8; ++kt) {
        if constexpr (FAST) {
          hr[kt][0] = s_ld64(hb + kt * 8 + l16 * 2);
          hr[kt][1] = s_ld64(hb + kt * 8 + l16 * 2 + 1);
        } else {
          hr[kt][0] = a_ld64(hb + kt * 8 + l16 * 2);
          hr[kt][1] = a_ld64(hb + kt * 8 + l16 * 2 + 1);
        }
      }
      if constexpr (FAST) { vm0(); sb0(); }
#pragma unroll
      for (int kt = 0; kt < 8; ++kt) {
        union { u64 q[2]; bf16x8 v; } cv;
        cv.q[0] = hr[kt][0]; cv.q[1] = hr[kt][1];
#pragma unroll
        for (int nt = 0; nt < 4; ++nt) acc[nt] = mm(cv.v, ufr[kt][nt], acc[nt]);
      }
    }

    // ---- gate tiles -> LDS (cross-wave exchange) ----
#pragma unroll
    for (int nt = 0; nt < 4; ++nt)
#pragma unroll
      for (int r = 0; r < 4; ++r)
        gl[w][l16 * 4 + r][nt * 16 + l15] = acc[nt][r];
    __syncthreads();

    // ---- pointwise cell update (Keras order i, f, cbar, o) ----
    f32x4 gi = *reinterpret_cast<const f32x4*>(&gl[0][prow][ublk * 4]);
    f32x4 gf = *reinterpret_cast<const f32x4*>(&gl[1][prow][ublk * 4]);
    f32x4 gc = *reinterpret_cast<const f32x4*>(&gl[2][prow][ublk * 4]);
    f32x4 go = *reinterpret_cast<const f32x4*>(&gl[3][prow][ublk * 4]);
    float hh[4];
#pragma unroll
    for (int q = 0; q < 4; ++q) {
      float iv = sigm(gi[q] + bv[0][q]);
      float fv = sigm(gf[q] + bv[1][q]);
      float cd = tanh_(gc[q] + bv[2][q]);
      float ov = sigm(go[q] + bv[3][q]);
      cst[q] = fv * cst[q] + iv * cd;
      hh[q] = ov * tanh_(cst[q]);
    }
    union { u16 s[4]; u64 q; } hp;
#pragma unroll
    for (int q = 0; q < 4; ++q) hp.s[q] = f2bf(hh[q]);

    // ---- publish h_t at the chain's coherence point ----
    u64* hw;
    if constexpr (IS1) hw = hseq + ((long)b * NT + t) * 64 + (ucol >> 2);
    else               hw = h2 + ((((long)(t & 1) * 8 + g) * 16) + prow) * 64 + (ucol >> 2);
    if constexpr (FAST) s_st64(hw, hp.q); else a_st64(hw, hp.q);
    if constexpr (!IS1) {
      if (t == NT - 1)
        *reinterpret_cast<f32x4*>(hlast + (long)b * NH + ucol) =
            f32x4{hh[0], hh[1], hh[2], hh[3]};
    }

    // ---- completion signal ----
    if constexpr (FAST) {
      vm0();                 // this wave's h stores are at the L2 coh. point
      __syncthreads();       // all 4 waves done (also protects gl reuse)
      if (tid == 0) s_st32(mytag, (u32)(t + 1));
    } else {
      vm0();                 // round-4 proven: per-wave bump, no extra barrier
      if (lane == 0) a_add32(IS1 ? c1 : c2, 1u);
    }
  }
}

// ---------------------------------------------------------------------------
__global__ __launch_bounds__(256, 1) void lstm_fused(
    const float* __restrict__ x,
    const float* __restrict__ W1, const float* __restrict__ U1, const float* __restrict__ b1,
    const float* __restrict__ W2, const float* __restrict__ U2, const float* __restrict__ b2,
    u64* hseq, u64* h2, u32* flags, float* hlast)
{
  __shared__ __align__(16) float gl[4][16][68];
  __shared__ u32 planS;
  const int tid = threadIdx.x;

  // ---- phase 1: registration against ACTUAL placement (agent atomics) ----
  if (tid == 0) {
    u32 xcc = 0;
    asm volatile("s_getreg_b32 %0, hwreg(HW_REG_XCC_ID)" : "=s"(xcc));
    xcc &= 7u;
    u32 slot = a_addret(flags + REGX_OFF + xcc * 16, 1u);
    vm0();   // RMW response received => visible at MALL before next add
    a_add32(flags + REGC_OFF, 1u);
    long bud = 50000000; bool ok = true;
    while (a_ld32(flags + REGC_OFF) < 64u) { if (--bud <= 0) { ok = false; break; } }
    asm volatile("" ::: "memory");
    u32 grp, role, fast = 0;
    if (ok) {
      u32 nx[8], full[8], F = 0;
#pragma unroll
      for (int y = 0; y < 8; ++y) { nx[y] = a_ld32(flags + REGX_OFF + y * 16); full[y] = nx[y] >> 3; F += full[y]; }
      u32 cbase = 0, sbase = 0;
      for (u32 y = 0; y < xcc; ++y) { cbase += full[y]; sbase += nx[y] - 8u * full[y]; }
      if (slot < 8u * full[xcc]) {            // member of a formed local chain
        fast = 1u; grp = cbase + (slot >> 3); role = slot & 7u;
      } else {                                 // spare -> covers leftover group
        u32 si = sbase + (slot - 8u * full[xcc]);
        grp = F + (si >> 3); role = si & 7u;
      }
      if (grp > 7u) { grp &= 7u; fast = 0u; }  // safety clamp (unreachable)
    } else {                                   // static fallback, agent mode
      grp = blockIdx.x & 7u;
      role = ((blockIdx.x >> 3) & 3u) + (blockIdx.x >= 32 ? 4u : 0u);
    }
    planS = fast | (grp << 1) | (role << 4);
  }
  __syncthreads();
  u32 plan = planS;
  bool fast = plan & 1u;
  const int g = (plan >> 1) & 7, role = (plan >> 4) & 7;
  const bool is1 = role < 4;
  const int j = role & 3;

  // ---- phase 2: sc0 ping-ring liveness + chain agreement (fast only) ----
  if (fast) {
    if (tid == 0) {
      bool fail = false;
      u32* ping = flags + PING_OFF + g * 64;
      u32* slotp = ping + role;
      u32* prevp = ping + ((role + 7) & 7);
      for (u32 k = 1; k <= 2u && !fail; ++k) {
        if (role == 0) {
          s_st32(slotp, k);
          long pb = 100000;
          while (s_ld32w(prevp) < k) { if (--pb <= 0) { fail = true; break; } }
        } else {
          long pb = 100000;
          while (s_ld32w(prevp) < k) { if (--pb <= 0) { fail = true; break; } }
          if (!fail) s_st32(slotp, k);
        }
      }
      vm0();
      if (fail) a_st32(flags + ABRT_OFF + g, 1u);
      vm0();
      a_add32(flags + DONE_OFF + g, 1u);
      long db = 20000000; bool jok = true;
      while (a_ld32(flags + DONE_OFF + g) < 8u) { if (--db <= 0) { jok = false; break; } }
      asm volatile("" ::: "memory");
      if (!jok || a_ld32(flags + ABRT_OFF + g) != 0u) planS = plan & ~1u;
    }
    __syncthreads();
    plan = planS; fast = plan & 1u;
  }

  // ---- phase 3: the scans (mode chain-uniform; groups independent) ----
  if (is1) {
    if (fast) scan<true,  true >(U1, W1, b1, x, hseq, h2, flags, hlast, g, j, gl);
    else      scan<true,  false>(U1, W1, b1, x, hseq, h2, flags, hlast, g, j, gl);
  } else {
    if (fast) scan<false, true >(U2, W2, b2, nullptr, hseq, h2, flags, hlast, g, j, gl);
    else      scan<false, false>(U2, W2, b2, nullptr, hseq, h2, flags, hlast, g, j, gl);
  }
}

// ---------------------------------------------------------------------------
__global__ void dense_out(const float* __restrict__ hl, const float* __restrict__ Wd,
                          const float* __restrict__ bd, float* __restrict__ out) {
  int b = blockIdx.x, l = threadIdx.x;
  f32x4 h  = *reinterpret_cast<const f32x4*>(hl + (long)b * NH + l * 4);
  f32x4 wv = *reinterpret_cast<const f32x4*>(Wd + l * 4);
  float s = h[0] * wv[0] + h[1] * wv[1] + h[2] * wv[2] + h[3] * wv[3];
#pragma unroll
  for (int off = 32; off > 0; off >>= 1) s += __shfl_down(s, off);
  if (l == 0) out[b] = fmaxf(s + bd[0], 0.f);
}

// ---------------------------------------------------------------------------
extern "C" void kernel_launch(void* const* d_in, const int* in_sizes, int n_in,
                              void* d_out, int out_size, void* d_ws, size_t ws_size,
                              hipStream_t stream) {
  const float* x  = (const float*)d_in[0];
  const float* W1 = (const float*)d_in[1];
  const float* U1 = (const float*)d_in[2];
  const float* b1 = (const float*)d_in[3];
  const float* W2 = (const float*)d_in[4];
  const float* U2 = (const float*)d_in[5];
  const float* b2 = (const float*)d_in[6];
  const float* Wd = (const float*)d_in[7];
  const float* bd = (const float*)d_in[8];
  float* out = (float*)d_out;

  char* ws = (char*)d_ws;
  size_t off = 0;
  auto alloc = [&](size_t bytes) -> char* {
    char* p = ws + off;
    off = (off + bytes + 255) & ~(size_t)255;
    return p;
  };
  u64*   hseq  = (u64*)  alloc((size_t)M_ROWS * NH * 2);       // 64 MiB
  u64*   h2    = (u64*)  alloc((size_t)2 * 8 * 16 * NH * 2);   // 128 KiB
  float* hlast = (float*)alloc((size_t)NB * NH * 4);           // 128 KiB
  u32*   flags = (u32*)  alloc(FLAGS_N * 4);                   // 8 KiB

  if (off > ws_size) {
    // workspace too small: finite sentinel 0x42424242 ~= 48.56 (NOT NaN)
    hipMemsetAsync(d_out, 0x42, (size_t)out_size * sizeof(float), stream);
    return;
  }

  prep<<<8, 256, 0, stream>>>(flags);
  lstm_fused<<<64, 256, 0, stream>>>(x, W1, U1, b1, W2, U2, b2, hseq, h2, flags, hlast);
  dense_out<<<128, 64, 0, stream>>>(hlast, Wd, bd, out);
}

// Round 7
// 6278.359 us; speedup vs baseline: 2.5032x; 2.5032x over previous
//
#include <hip/hip_runtime.h>

typedef __bf16 bf16x8 __attribute__((ext_vector_type(8)));
typedef float  f32x4  __attribute__((ext_vector_type(4)));
typedef unsigned short u16;
typedef unsigned int   u32;
typedef unsigned long long u64;

#define NB 128      // batch
#define NT 1024     // time steps
#define NF 128      // input features
#define NH 256      // hidden units
#define NG 1024     // 4*NH gate columns
#define M_ROWS (NB*NT)

__device__ __forceinline__ u16 f2bf(float f) {
  union { float f; u32 u; } c; c.f = f;
  u32 u = c.u;
  return (u16)((u + 0x7fffu + ((u >> 16) & 1u)) >> 16);   // RNE
}
__device__ __forceinline__ float sigm(float x) { return 1.f / (1.f + __expf(-x)); }
__device__ __forceinline__ float tanh_(float x) { return 1.f - 2.f / (1.f + __expf(2.f * x)); }
__device__ __forceinline__ f32x4 mm(bf16x8 a, bf16x8 b, f32x4 c) {
  return __builtin_amdgcn_mfma_f32_16x16x32_bf16(a, b, c, 0, 0, 0);
}
__device__ __forceinline__ void vm0() { asm volatile("s_waitcnt vmcnt(0)" ::: "memory"); }

// Relaxed AGENT atomics: coherent at the MALL by scope, no cache-maintenance
// ops. Ordering: producer = vm0 between data stores and counter add;
// consumer = tid0 poll -> __syncthreads -> loads (HW-proven round 4).
__device__ __forceinline__ u32 a_ld32(const u32* p) { return __hip_atomic_load((u32*)p, __ATOMIC_RELAXED, __HIP_MEMORY_SCOPE_AGENT); }
__device__ __forceinline__ u64 a_ld64(const u64* p) { return __hip_atomic_load((u64*)p, __ATOMIC_RELAXED, __HIP_MEMORY_SCOPE_AGENT); }
__device__ __forceinline__ void a_st64(u64* p, u64 v) { __hip_atomic_store(p, v, __ATOMIC_RELAXED, __HIP_MEMORY_SCOPE_AGENT); }
__device__ __forceinline__ void a_add32(u32* p, u32 v) { __hip_atomic_fetch_add(p, v, __ATOMIC_RELAXED, __HIP_MEMORY_SCOPE_AGENT); }

// ---------------------------------------------------------------------------
__global__ void prep(u32* __restrict__ flags) {
  if (blockIdx.x == 0 && threadIdx.x < 256) flags[threadIdx.x] = 0;
}

// ---------------------------------------------------------------------------
// Fused 2-layer LSTM scan (round-4 structure). 64 WGs: bid<32 -> L1, else L2.
// Per layer: 8 groups (16 batch rows) x 4 WGs (unit-quarter). 256 thr =
// 4 waves; wave w = Keras gate w. Resident per wave: U frags (128 VGPR) +
// W frags (KIN/2 VGPR).
// Sync per group: counters c1/c2 (16 adds per step: 4 WGs x 4 waves).
//   L1 step t: poll c1 >= 16t         -> read hseq[t-1]
//   L2 step t: poll c1 >= 16(t+1) AND c2 >= 16t (ONE spin, ONE barrier)
//              -> read hseq[t] (feed) and h2[(t-1)&1] together (overlapped)
// Polls: tid0-only with s_sleep(1) backoff (contention fix), barrier
// broadcast. Producers: data stores -> vm0 -> per-wave lane0 add (round 4).
// ---------------------------------------------------------------------------
template<bool IS1>
__device__ void scan(const float* __restrict__ U, const float* __restrict__ W,
                     const float* __restrict__ bias, const float* __restrict__ xf,
                     u64* hseq, u64* h2, u32* c1, u32* c2, float* hlast,
                     int g, int j, float (*gl)[16][68])
{
  const int tid = threadIdx.x, lane = tid & 63, w = tid >> 6;
  const int l15 = lane & 15, l16 = lane >> 4;
  constexpr int KIN  = IS1 ? NF : NH;
  constexpr int KTIN = KIN / 32;
  const int colb = w * NH + j * 64;

  // Resident W frags (B-operand), K = KIN
  bf16x8 wfr[KTIN][4];
#pragma unroll
  for (int kt = 0; kt < KTIN; ++kt) {
    const int k0 = kt * 32 + l16 * 8;
#pragma unroll
    for (int nt = 0; nt < 4; ++nt) {
      const float* wp = W + (long)k0 * NG + colb + nt * 16 + l15;
      union { u16 s[8]; bf16x8 v; } cv;
#pragma unroll
      for (int e = 0; e < 8; ++e) cv.s[e] = f2bf(wp[(long)e * NG]);
      wfr[kt][nt] = cv.v;
    }
  }
  // Resident U frags (B-operand), K = NH
  bf16x8 ufr[8][4];
#pragma unroll
  for (int kt = 0; kt < 8; ++kt) {
    const int k0 = kt * 32 + l16 * 8;
#pragma unroll
    for (int nt = 0; nt < 4; ++nt) {
      const float* up = U + (long)k0 * NG + colb + nt * 16 + l15;
      union { u16 s[8]; bf16x8 v; } cv;
#pragma unroll
      for (int e = 0; e < 8; ++e) cv.s[e] = f2bf(up[(long)e * NG]);
      ufr[kt][nt] = cv.v;
    }
  }

  const int prow = tid & 15, ublk = tid >> 4;
  const int b = g * 16 + prow, ucol = j * 64 + ublk * 4;

  float bv[4][4];
#pragma unroll
  for (int gg = 0; gg < 4; ++gg)
#pragma unroll
    for (int q = 0; q < 4; ++q) bv[gg][q] = bias[gg * NH + ucol + q];

  const long abatch = (long)(g * 16 + l15) * NT;   // A-frag batch row base

  float cst[4] = {0.f, 0.f, 0.f, 0.f};
  long budget = 2000000;      // tid0-only; sleep-spaced; bail, never hang
  bool dead = false;          // meaningful in tid0 only

  for (int t = 0; t < NT; ++t) {
    bf16x8 ax[KTIN];

    if constexpr (IS1) {
      // ---- x loads + cvt + x@W MFMAs (ungated; overlaps prior adds) ----
      const float* xp0 = xf + (abatch + t) * NF;
      f32x4 xraw[KTIN][2];
#pragma unroll
      for (int kt = 0; kt < KTIN; ++kt) {
        const float* xp = xp0 + kt * 32 + l16 * 8;
        xraw[kt][0] = *reinterpret_cast<const f32x4*>(xp);
        xraw[kt][1] = *reinterpret_cast<const f32x4*>(xp + 4);
      }
#pragma unroll
      for (int kt = 0; kt < KTIN; ++kt) {
        union { u16 s[8]; bf16x8 v; } cv;
#pragma unroll
        for (int e = 0; e < 4; ++e) {
          cv.s[e] = f2bf(xraw[kt][0][e]); cv.s[4 + e] = f2bf(xraw[kt][1][e]);
        }
        ax[kt] = cv.v;
      }
      f32x4 acc[4] = {};
#pragma unroll
      for (int kt = 0; kt < KTIN; ++kt)
#pragma unroll
        for (int nt = 0; nt < 4; ++nt) acc[nt] = mm(ax[kt], wfr[kt][nt], acc[nt]);

      // ---- poll (tid0 + sleep), barrier broadcast ----
      if (t > 0) {
        if (tid == 0 && !dead) {
          const u32 tgt = 16u * (u32)t;
          while (a_ld32(c1) < tgt) {
            __builtin_amdgcn_s_sleep(1);
            if (--budget <= 0) { dead = true; break; }
          }
        }
        __syncthreads();
        asm volatile("" ::: "memory");
        // ---- h_{t-1} loads + U MFMAs ----
        const u64* hb = hseq + (abatch + (t - 1)) * 64;
        u64 hr[8][2];
#pragma unroll
        for (int kt = 0; kt < 8; ++kt) {
          hr[kt][0] = a_ld64(hb + kt * 8 + l16 * 2);
          hr[kt][1] = a_ld64(hb + kt * 8 + l16 * 2 + 1);
        }
#pragma unroll
        for (int kt = 0; kt < 8; ++kt) {
          union { u64 q[2]; bf16x8 v; } cv;
          cv.q[0] = hr[kt][0]; cv.q[1] = hr[kt][1];
#pragma unroll
          for (int nt = 0; nt < 4; ++nt) acc[nt] = mm(cv.v, ufr[kt][nt], acc[nt]);
        }
      }
      // stash acc via gl below
#pragma unroll
      for (int nt = 0; nt < 4; ++nt)
#pragma unroll
        for (int r = 0; r < 4; ++r)
          gl[w][l16 * 4 + r][nt * 16 + l15] = acc[nt][r];
    } else {
      // ---- L2: ONE merged spin (feed c1 + recurrence c2), ONE barrier ----
      if (tid == 0 && !dead) {
        const u32 tgtF = 16u * (u32)(t + 1);
        const u32 tgtR = 16u * (u32)t;
        for (;;) {
          u32 v1 = a_ld32(c1);
          u32 v2 = (t > 0) ? a_ld32(c2) : tgtR;
          if (v1 >= tgtF && v2 >= tgtR) break;
          __builtin_amdgcn_s_sleep(1);
          if (--budget <= 0) { dead = true; break; }
        }
      }
      __syncthreads();
      asm volatile("" ::: "memory");

      // ---- issue feed (hseq[t]) AND recurrence (h2) loads together ----
      const u64* xb = hseq + (abatch + t) * 64;
      u64 xr[KTIN][2];
#pragma unroll
      for (int kt = 0; kt < KTIN; ++kt) {
        xr[kt][0] = a_ld64(xb + kt * 8 + l16 * 2);
        xr[kt][1] = a_ld64(xb + kt * 8 + l16 * 2 + 1);
      }
      u64 hr[8][2];
      if (t > 0) {
        const u64* hb = h2 + ((((long)((t + 1) & 1) * 8 + g) * 16) + l15) * 64;
#pragma unroll
        for (int kt = 0; kt < 8; ++kt) {
          hr[kt][0] = a_ld64(hb + kt * 8 + l16 * 2);
          hr[kt][1] = a_ld64(hb + kt * 8 + l16 * 2 + 1);
        }
      }
      // ---- x@W on the feed (rec loads still in flight) ----
#pragma unroll
      for (int kt = 0; kt < KTIN; ++kt) {
        union { u64 q[2]; bf16x8 v; } cv;
        cv.q[0] = xr[kt][0]; cv.q[1] = xr[kt][1];
        ax[kt] = cv.v;
      }
      f32x4 acc[4] = {};
#pragma unroll
      for (int kt = 0; kt < KTIN; ++kt)
#pragma unroll
        for (int nt = 0; nt < 4; ++nt) acc[nt] = mm(ax[kt], wfr[kt][nt], acc[nt]);
      if (t > 0) {
#pragma unroll
        for (int kt = 0; kt < 8; ++kt) {
          union { u64 q[2]; bf16x8 v; } cv;
          cv.q[0] = hr[kt][0]; cv.q[1] = hr[kt][1];
#pragma unroll
          for (int nt = 0; nt < 4; ++nt) acc[nt] = mm(cv.v, ufr[kt][nt], acc[nt]);
        }
      }
#pragma unroll
      for (int nt = 0; nt < 4; ++nt)
#pragma unroll
        for (int r = 0; r < 4; ++r)
          gl[w][l16 * 4 + r][nt * 16 + l15] = acc[nt][r];
    }

    // ---- cross-wave gate exchange + pointwise (identical arithmetic) ----
    __syncthreads();
    f32x4 gi = *reinterpret_cast<const f32x4*>(&gl[0][prow][ublk * 4]);
    f32x4 gf = *reinterpret_cast<const f32x4*>(&gl[1][prow][ublk * 4]);
    f32x4 gc = *reinterpret_cast<const f32x4*>(&gl[2][prow][ublk * 4]);
    f32x4 go = *reinterpret_cast<const f32x4*>(&gl[3][prow][ublk * 4]);
    float hh[4];
#pragma unroll
    for (int q = 0; q < 4; ++q) {
      float iv = sigm(gi[q] + bv[0][q]);
      float fv = sigm(gf[q] + bv[1][q]);
      float cd = tanh_(gc[q] + bv[2][q]);
      float ov = sigm(go[q] + bv[3][q]);
      cst[q] = fv * cst[q] + iv * cd;
      hh[q] = ov * tanh_(cst[q]);
    }
    union { u16 s[4]; u64 q; } hp;
#pragma unroll
    for (int q = 0; q < 4; ++q) hp.s[q] = f2bf(hh[q]);

    // ---- publish h_t (relaxed agent -> MALL), then vm0 + per-wave add ----
    if constexpr (IS1) {
      a_st64(hseq + ((long)b * NT + t) * 64 + (ucol >> 2), hp.q);
    } else {
      a_st64(h2 + ((((long)(t & 1) * 8 + g) * 16) + prow) * 64 + (ucol >> 2), hp.q);
      if (t == NT - 1)
        *reinterpret_cast<f32x4*>(hlast + (long)b * NH + ucol) =
            f32x4{hh[0], hh[1], hh[2], hh[3]};
    }
    vm0();   // data at coherence point before the signal
    if (lane == 0) a_add32(IS1 ? c1 : c2, 1u);
    // NOTE: next step's gl writes are gated on all 16 wave-adds of this
    // group (poll), each of which follows that wave's gl reads -> no WAR
    // race on gl without a second barrier (round-4-proven structure).
  }
}

// ---------------------------------------------------------------------------
__global__ __launch_bounds__(256, 1) void lstm_fused(
    const float* __restrict__ x,
    const float* __restrict__ W1, const float* __restrict__ U1, const float* __restrict__ b1,
    const float* __restrict__ W2, const float* __restrict__ U2, const float* __restrict__ b2,
    u64* hseq, u64* h2, u32* flags, float* hlast)
{
  __shared__ __align__(16) float gl[4][16][68];
  const int bid = blockIdx.x;
  const int sb  = bid & 31, g = sb & 7, j = sb >> 3;
  u32* c1 = flags + g * 16;          // 16 adds/step (4 WGs x 4 waves)
  u32* c2 = flags + 128 + g * 16;
  if (bid < 32)
    scan<true >(U1, W1, b1, x, hseq, h2, c1, c2, nullptr, g, j, gl);
  else
    scan<false>(U2, W2, b2, nullptr, hseq, h2, c1, c2, hlast, g, j, gl);
}

// ---------------------------------------------------------------------------
__global__ void dense_out(const float* __restrict__ hl, const float* __restrict__ Wd,
                          const float* __restrict__ bd, float* __restrict__ out) {
  int b = blockIdx.x, l = threadIdx.x;
  f32x4 h  = *reinterpret_cast<const f32x4*>(hl + (long)b * NH + l * 4);
  f32x4 wv = *reinterpret_cast<const f32x4*>(Wd + l * 4);
  float s = h[0] * wv[0] + h[1] * wv[1] + h[2] * wv[2] + h[3] * wv[3];
#pragma unroll
  for (int off = 32; off > 0; off >>= 1) s += __shfl_down(s, off);
  if (l == 0) out[b] = fmaxf(s + bd[0], 0.f);
}

// ---------------------------------------------------------------------------
extern "C" void kernel_launch(void* const* d_in, const int* in_sizes, int n_in,
                              void* d_out, int out_size, void* d_ws, size_t ws_size,
                              hipStream_t stream) {
  const float* x  = (const float*)d_in[0];
  const float* W1 = (const float*)d_in[1];
  const float* U1 = (const float*)d_in[2];
  const float* b1 = (const float*)d_in[3];
  const float* W2 = (const float*)d_in[4];
  const float* U2 = (const float*)d_in[5];
  const float* b2 = (const float*)d_in[6];
  const float* Wd = (const float*)d_in[7];
  const float* bd = (const float*)d_in[8];
  float* out = (float*)d_out;

  char* ws = (char*)d_ws;
  size_t off = 0;
  auto alloc = [&](size_t bytes) -> char* {
    char* p = ws + off;
    off = (off + bytes + 255) & ~(size_t)255;
    return p;
  };
  u64*   hseq  = (u64*)  alloc((size_t)M_ROWS * NH * 2);       // 64 MiB
  u64*   h2    = (u64*)  alloc((size_t)2 * 8 * 16 * NH * 2);   // 128 KiB
  float* hlast = (float*)alloc((size_t)NB * NH * 4);           // 128 KiB
  u32*   flags = (u32*)  alloc(1024);

  if (off > ws_size) {
    // workspace too small: finite sentinel 0x42424242 ~= 48.56 (NOT NaN)
    hipMemsetAsync(d_out, 0x42, (size_t)out_size * sizeof(float), stream);
    return;
  }

  prep<<<1, 256, 0, stream>>>(flags);
  lstm_fused<<<64, 256, 0, stream>>>(x, W1, U1, b1, W2, U2, b2, hseq, h2, flags, hlast);
  dense_out<<<128, 64, 0, stream>>>(hlast, Wd, bd, out);
}